// Round 2
// baseline (1211.021 us; speedup 1.0000x reference)
//
#include <hip/hip_runtime.h>
#include <hip/hip_bf16.h>
#include <math.h>

#define D_MODEL 768
#define D_STATE 16
#define D_CONV  4
#define D_INNER 1536
#define DT_RANK 48
#define BATCH   2
#define SEQ     1024
#define NROWS   (BATCH*SEQ)      // 2048
#define DBC_N   (DT_RANK + 2*D_STATE) // 80

__device__ __forceinline__ float siluf(float x){ return x / (1.0f + expf(-x)); }

// ---------------- RMSNorm: one block per row (768 elems, 256 thr x3) ----------
__global__ __launch_bounds__(256) void k_rmsnorm(const float* __restrict__ x,
                                                 const float* __restrict__ w,
                                                 float* __restrict__ h){
    int r = blockIdx.x;
    const float* xr = x + (size_t)r * D_MODEL;
    float v[3]; float ss = 0.f;
    #pragma unroll
    for (int i = 0; i < 3; i++){
        v[i] = xr[threadIdx.x + i*256];
        ss += v[i]*v[i];
    }
    #pragma unroll
    for (int o = 1; o < 64; o <<= 1) ss += __shfl_xor(ss, o, 64);
    __shared__ float red[4];
    int wave = threadIdx.x >> 6, lane = threadIdx.x & 63;
    if (lane == 0) red[wave] = ss;
    __syncthreads();
    float tot = red[0] + red[1] + red[2] + red[3];
    float scale = rsqrtf(tot * (1.0f/768.0f) + 1e-6f);
    #pragma unroll
    for (int i = 0; i < 3; i++){
        int idx = threadIdx.x + i*256;
        h[(size_t)r*D_MODEL + idx] = v[i] * scale * w[idx];
    }
}

// ---------------- Generic 64x64 tile fp32 GEMM, A fp32 MxK, B fp32 KxN --------
// EPI=0: C fp32.  EPI=1: C = acc + residual(fp32), stored fp32.
template<int EPI>
__global__ __launch_bounds__(256) void k_gemm64(const float* __restrict__ A,
                                                const float* __restrict__ B,
                                                float* __restrict__ C,
                                                const float* __restrict__ res,
                                                int M, int N, int K){
    __shared__ float As[16][68];   // [k][row], padded
    __shared__ float Bs[16][68];   // [k][col], padded
    int t = threadIdx.x;
    int row0 = blockIdx.y * 64, col0 = blockIdx.x * 64;
    int tr = t >> 4, tc = t & 15;
    int arow = t >> 4, acol = t & 15;    // A tile loader: 16 rows x 16 cols per pass
    int bcol = t & 63, brow = t >> 6;    // B tile loader: 4 rows x 64 cols per pass
    float acc[4][4] = {};
    for (int k0 = 0; k0 < K; k0 += 16){
        #pragma unroll
        for (int m = 0; m < 4; m++)
            As[acol][arow + 16*m] = A[(size_t)(row0 + arow + 16*m)*K + k0 + acol];
        #pragma unroll
        for (int m = 0; m < 4; m++)
            Bs[brow + 4*m][bcol] = B[(size_t)(k0 + brow + 4*m)*N + col0 + bcol];
        __syncthreads();
        #pragma unroll
        for (int kk = 0; kk < 16; kk++){
            float4 a4 = *(const float4*)&As[kk][tr*4];
            float4 b4 = *(const float4*)&Bs[kk][tc*4];
            float av[4] = {a4.x, a4.y, a4.z, a4.w};
            float bv[4] = {b4.x, b4.y, b4.z, b4.w};
            #pragma unroll
            for (int i = 0; i < 4; i++)
                #pragma unroll
                for (int j = 0; j < 4; j++)
                    acc[i][j] += av[i] * bv[j];
        }
        __syncthreads();
    }
    #pragma unroll
    for (int i = 0; i < 4; i++){
        int row = row0 + tr*4 + i;
        #pragma unroll
        for (int j = 0; j < 4; j++){
            int col = col0 + tc*4 + j;
            float v = acc[i][j];
            if (EPI == 1) v += res[(size_t)row*N + col];
            C[(size_t)row*N + col] = v;
        }
    }
}

// ---------------- causal depthwise conv (width 4) + bias + SiLU ---------------
__global__ __launch_bounds__(256) void k_conv(const float* __restrict__ xz,
                                              const float* __restrict__ cw,
                                              const float* __restrict__ cb,
                                              float* __restrict__ xc){
    int idx = blockIdx.x * 256 + threadIdx.x;   // over NROWS*D_INNER
    int d = idx % D_INNER;
    int r = idx / D_INNER;
    int l = r % SEQ;
    float acc = cb[d];
    #pragma unroll
    for (int k = 0; k < 4; k++){
        int ls = l - 3 + k;
        if (ls >= 0)
            acc += xz[(size_t)(r - 3 + k)*3072 + d] * cw[d*4 + k];
    }
    xc[idx] = siluf(acc);
}

// ---------------- x-proj: dbc[r, 0..79] = xc[r,:] @ x_proj_w ------------------
__global__ __launch_bounds__(128) void k_xproj(const float* __restrict__ xc,
                                               const float* __restrict__ w,
                                               float* __restrict__ dbc){
    __shared__ float row[D_INNER];
    int r = blockIdx.x;
    for (int i = threadIdx.x; i < D_INNER; i += 128)
        row[i] = xc[(size_t)r*D_INNER + i];
    __syncthreads();
    int j = threadIdx.x;
    if (j < DBC_N){
        float acc = 0.f;
        #pragma unroll 8
        for (int k = 0; k < D_INNER; k++)
            acc += row[k] * w[k*DBC_N + j];
        dbc[(size_t)r*DBC_N + j] = acc;
    }
}

// ---------------- dt-proj (K=48) + bias + softplus ----------------------------
__global__ __launch_bounds__(256) void k_dtproj(const float* __restrict__ dbc,
                                                const float* __restrict__ w,
                                                const float* __restrict__ bias,
                                                float* __restrict__ dt){
    int r = blockIdx.y;
    int j = blockIdx.x * 256 + threadIdx.x;   // 0..1535
    __shared__ float dl[DT_RANK];
    if (threadIdx.x < DT_RANK) dl[threadIdx.x] = dbc[(size_t)r*DBC_N + threadIdx.x];
    __syncthreads();
    float acc = bias[j];
    #pragma unroll
    for (int k = 0; k < DT_RANK; k++)
        acc += dl[k] * w[k*D_INNER + j];
    dt[(size_t)r*D_INNER + j] = (acc > 20.f) ? acc : log1pf(expf(acc));
}

// ---------------- selective scan: one thread per (b, d, n) --------------------
// h_t = exp(dt*A)*h_{t-1} + dt*xc*B_t ; y = sum_n h*C + D*xc ; gate silu(z)
__global__ __launch_bounds__(256) void k_scan(const float* __restrict__ dt,
                                              const float* __restrict__ xc,
                                              const float* __restrict__ dbc,
                                              const float* __restrict__ xz,
                                              const float* __restrict__ A_log,
                                              const float* __restrict__ Dp,
                                              float* __restrict__ y){
    int t = blockIdx.x * 256 + threadIdx.x;
    int n = t & 15;
    int dall = t >> 4;              // 0..3071
    int d = dall % D_INNER;
    int b = dall / D_INNER;
    float A = -expf(A_log[d*D_STATE + n]);
    float Dv = Dp[d];
    float h = 0.f;
    int rbase = b * SEQ;
    for (int l = 0; l < SEQ; l++){
        int r = rbase + l;
        float dtv = dt[(size_t)r*D_INNER + d];
        float xcv = xc[(size_t)r*D_INNER + d];
        float Bm  = dbc[(size_t)r*DBC_N + DT_RANK + n];
        float Cm  = dbc[(size_t)r*DBC_N + DT_RANK + D_STATE + n];
        float a = expf(dtv * A);
        h = a*h + dtv*xcv*Bm;
        float c = h * Cm;
        c += __shfl_xor(c, 1, 16);
        c += __shfl_xor(c, 2, 16);
        c += __shfl_xor(c, 4, 16);
        c += __shfl_xor(c, 8, 16);
        if (n == 0){
            float z = xz[(size_t)r*(2*D_INNER) + D_INNER + d];
            y[(size_t)r*D_INNER + d] = (c + Dv*xcv) * siluf(z);
        }
    }
}

extern "C" void kernel_launch(void* const* d_in, const int* in_sizes, int n_in,
                              void* d_out, int out_size, void* d_ws, size_t ws_size,
                              hipStream_t stream) {
    const float* x         = (const float*)d_in[0];
    const float* norm_w    = (const float*)d_in[1];
    const float* in_proj_w = (const float*)d_in[2];
    const float* conv_w    = (const float*)d_in[3];
    const float* conv_b    = (const float*)d_in[4];
    const float* x_proj_w  = (const float*)d_in[5];
    const float* dt_proj_w = (const float*)d_in[6];
    const float* dt_proj_b = (const float*)d_in[7];
    const float* A_log     = (const float*)d_in[8];
    const float* Dp        = (const float*)d_in[9];
    const float* out_proj_w= (const float*)d_in[10];
    float* out = (float*)d_out;

    float* ws  = (float*)d_ws;
    float* h   = ws;                               // 2048*768
    float* xz  = h   + (size_t)NROWS*D_MODEL;      // 2048*3072
    float* xc  = xz  + (size_t)NROWS*2*D_INNER;    // 2048*1536
    float* dbc = xc  + (size_t)NROWS*D_INNER;      // 2048*80
    float* dtb = dbc + (size_t)NROWS*DBC_N;        // 2048*1536
    float* y   = dtb + (size_t)NROWS*D_INNER;      // 2048*1536

    k_rmsnorm<<<NROWS, 256, 0, stream>>>(x, norm_w, h);

    dim3 g1(2*D_INNER/64, NROWS/64);   // (48, 32)
    k_gemm64<0><<<g1, 256, 0, stream>>>(h, in_proj_w, xz, nullptr,
                                        NROWS, 2*D_INNER, D_MODEL);

    k_conv<<<(NROWS*D_INNER)/256, 256, 0, stream>>>(xz, conv_w, conv_b, xc);

    k_xproj<<<NROWS, 128, 0, stream>>>(xc, x_proj_w, dbc);

    dim3 g2(D_INNER/256, NROWS);
    k_dtproj<<<g2, 256, 0, stream>>>(dbc, dt_proj_w, dt_proj_b, dtb);

    k_scan<<<(BATCH*D_INNER*D_STATE)/256, 256, 0, stream>>>(dtb, xc, dbc, xz,
                                                            A_log, Dp, y);

    dim3 g3(D_MODEL/64, NROWS/64);     // (12, 32)
    k_gemm64<1><<<g3, 256, 0, stream>>>(y, out_proj_w, out, x,
                                        NROWS, D_MODEL, D_INNER);
}

// Round 3
// 556.603 us; speedup vs baseline: 2.1757x; 2.1757x over previous
//
#include <hip/hip_runtime.h>
#include <hip/hip_bf16.h>
#include <math.h>

#define D_MODEL 768
#define D_STATE 16
#define D_CONV  4
#define D_INNER 1536
#define DT_RANK 48
#define BATCH   2
#define SEQ     1024
#define NROWS   (BATCH*SEQ)      // 2048
#define DBC_N   (DT_RANK + 2*D_STATE) // 80
#define NCHUNK  16
#define CHUNK   64               // SEQ / NCHUNK
#define SCAN_T  (BATCH*NCHUNK*D_INNER*D_STATE)   // 786432

__device__ __forceinline__ float siluf(float x){ return x / (1.0f + expf(-x)); }

// ---------------- RMSNorm: one block per row (768 elems, 256 thr x3) ----------
__global__ __launch_bounds__(256) void k_rmsnorm(const float* __restrict__ x,
                                                 const float* __restrict__ w,
                                                 float* __restrict__ h){
    int r = blockIdx.x;
    const float* xr = x + (size_t)r * D_MODEL;
    float v[3]; float ss = 0.f;
    #pragma unroll
    for (int i = 0; i < 3; i++){
        v[i] = xr[threadIdx.x + i*256];
        ss += v[i]*v[i];
    }
    #pragma unroll
    for (int o = 1; o < 64; o <<= 1) ss += __shfl_xor(ss, o, 64);
    __shared__ float red[4];
    int wave = threadIdx.x >> 6, lane = threadIdx.x & 63;
    if (lane == 0) red[wave] = ss;
    __syncthreads();
    float tot = red[0] + red[1] + red[2] + red[3];
    float scale = rsqrtf(tot * (1.0f/768.0f) + 1e-6f);
    #pragma unroll
    for (int i = 0; i < 3; i++){
        int idx = threadIdx.x + i*256;
        h[(size_t)r*D_MODEL + idx] = v[i] * scale * w[idx];
    }
}

// ---------------- Generic 64x64 tile fp32 GEMM, A fp32 MxK, B fp32 KxN --------
// EPI=0: C fp32.  EPI=1: C = acc + residual(fp32), stored fp32.
template<int EPI>
__global__ __launch_bounds__(256) void k_gemm64(const float* __restrict__ A,
                                                const float* __restrict__ B,
                                                float* __restrict__ C,
                                                const float* __restrict__ res,
                                                int M, int N, int K){
    __shared__ float As[16][68];   // [k][row], padded
    __shared__ float Bs[16][68];   // [k][col], padded
    int t = threadIdx.x;
    int row0 = blockIdx.y * 64, col0 = blockIdx.x * 64;
    int tr = t >> 4, tc = t & 15;
    int arow = t >> 4, acol = t & 15;
    int bcol = t & 63, brow = t >> 6;
    float acc[4][4] = {};
    for (int k0 = 0; k0 < K; k0 += 16){
        #pragma unroll
        for (int m = 0; m < 4; m++)
            As[acol][arow + 16*m] = A[(size_t)(row0 + arow + 16*m)*K + k0 + acol];
        #pragma unroll
        for (int m = 0; m < 4; m++)
            Bs[brow + 4*m][bcol] = B[(size_t)(k0 + brow + 4*m)*N + col0 + bcol];
        __syncthreads();
        #pragma unroll
        for (int kk = 0; kk < 16; kk++){
            float4 a4 = *(const float4*)&As[kk][tr*4];
            float4 b4 = *(const float4*)&Bs[kk][tc*4];
            float av[4] = {a4.x, a4.y, a4.z, a4.w};
            float bv[4] = {b4.x, b4.y, b4.z, b4.w};
            #pragma unroll
            for (int i = 0; i < 4; i++)
                #pragma unroll
                for (int j = 0; j < 4; j++)
                    acc[i][j] += av[i] * bv[j];
        }
        __syncthreads();
    }
    #pragma unroll
    for (int i = 0; i < 4; i++){
        int row = row0 + tr*4 + i;
        #pragma unroll
        for (int j = 0; j < 4; j++){
            int col = col0 + tc*4 + j;
            float v = acc[i][j];
            if (EPI == 1) v += res[(size_t)row*N + col];
            C[(size_t)row*N + col] = v;
        }
    }
}

// ---------------- causal depthwise conv (width 4) + bias + SiLU ---------------
__global__ __launch_bounds__(256) void k_conv(const float* __restrict__ xz,
                                              const float* __restrict__ cw,
                                              const float* __restrict__ cb,
                                              float* __restrict__ xc){
    int idx = blockIdx.x * 256 + threadIdx.x;   // over NROWS*D_INNER
    int d = idx % D_INNER;
    int r = idx / D_INNER;
    int l = r % SEQ;
    float acc = cb[d];
    #pragma unroll
    for (int k = 0; k < 4; k++){
        int ls = l - 3 + k;
        if (ls >= 0)
            acc += xz[(size_t)(r - 3 + k)*3072 + d] * cw[d*4 + k];
    }
    xc[idx] = siluf(acc);
}

// ---------------- x-proj: dbc[r, 0..79] = xc[r,:] @ x_proj_w ------------------
__global__ __launch_bounds__(128) void k_xproj(const float* __restrict__ xc,
                                               const float* __restrict__ w,
                                               float* __restrict__ dbc){
    __shared__ float row[D_INNER];
    int r = blockIdx.x;
    for (int i = threadIdx.x; i < D_INNER; i += 128)
        row[i] = xc[(size_t)r*D_INNER + i];
    __syncthreads();
    int j = threadIdx.x;
    if (j < DBC_N){
        float acc = 0.f;
        #pragma unroll 8
        for (int k = 0; k < D_INNER; k++)
            acc += row[k] * w[k*DBC_N + j];
        dbc[(size_t)r*DBC_N + j] = acc;
    }
}

// ---------------- dt-proj (K=48) + bias + softplus ----------------------------
__global__ __launch_bounds__(256) void k_dtproj(const float* __restrict__ dbc,
                                                const float* __restrict__ w,
                                                const float* __restrict__ bias,
                                                float* __restrict__ dt){
    int r = blockIdx.y;
    int j = blockIdx.x * 256 + threadIdx.x;   // 0..1535
    __shared__ float dl[DT_RANK];
    if (threadIdx.x < DT_RANK) dl[threadIdx.x] = dbc[(size_t)r*DBC_N + threadIdx.x];
    __syncthreads();
    float acc = bias[j];
    #pragma unroll
    for (int k = 0; k < DT_RANK; k++)
        acc += dl[k] * w[k*D_INNER + j];
    dt[(size_t)r*D_INNER + j] = (acc > 20.f) ? acc : log1pf(expf(acc));
}

// ================= chunked selective scan =====================================
// Recurrence h_l = a_l*h_{l-1} + b_l, a=exp(dt*A), b=dt*xc*B.
// Phase A: per (b,chunk,d,n) local scan -> Aprod (prod of a), Hloc (local final h)
// Phase B: serial combine over 16 chunks -> carry-in per chunk
// Phase C: re-walk chunk from carry, emit y = (sum_n h*C + D*xc)*silu(z)
// Thread index layout: t = ((b*NCHUNK + chunk)*D_INNER + d)*16 + n

__global__ __launch_bounds__(256) void k_scanA(const float* __restrict__ dt,
                                               const float* __restrict__ xc,
                                               const float* __restrict__ dbc,
                                               const float* __restrict__ A_log,
                                               float* __restrict__ Aprod,
                                               float* __restrict__ Hloc){
    int t = blockIdx.x * 256 + threadIdx.x;
    int n = t & 15;
    int d = (t >> 4) % D_INNER;
    int bc = t / (16*D_INNER);
    int chunk = bc % NCHUNK, b = bc / NCHUNK;
    float A = -expf(A_log[d*D_STATE + n]);
    float aP = 1.f, h = 0.f;
    int r0 = b*SEQ + chunk*CHUNK;
    for (int l = 0; l < CHUNK; l++){
        int r = r0 + l;
        float dtv = dt[(size_t)r*D_INNER + d];
        float xcv = xc[(size_t)r*D_INNER + d];
        float Bm  = dbc[(size_t)r*DBC_N + DT_RANK + n];
        float a = expf(dtv * A);
        h = a*h + dtv*xcv*Bm;
        aP *= a;
    }
    Aprod[t] = aP;
    Hloc[t]  = h;
}

__global__ __launch_bounds__(256) void k_scanB(const float* __restrict__ Aprod,
                                               const float* __restrict__ Hloc,
                                               float* __restrict__ carry){
    int t = blockIdx.x * 256 + threadIdx.x;    // over [b][d][n] = 49152
    int dn = t % (D_INNER*16);
    int b  = t / (D_INNER*16);
    float c = 0.f;
    for (int ch = 0; ch < NCHUNK; ch++){
        size_t idx = ((size_t)(b*NCHUNK + ch))*(D_INNER*16) + dn;
        carry[idx] = c;
        c = Aprod[idx]*c + Hloc[idx];
    }
}

__global__ __launch_bounds__(256) void k_scanC(const float* __restrict__ dt,
                                               const float* __restrict__ xc,
                                               const float* __restrict__ dbc,
                                               const float* __restrict__ xz,
                                               const float* __restrict__ A_log,
                                               const float* __restrict__ Dp,
                                               const float* __restrict__ carry,
                                               float* __restrict__ y){
    int t = blockIdx.x * 256 + threadIdx.x;
    int n = t & 15;
    int d = (t >> 4) % D_INNER;
    int bc = t / (16*D_INNER);
    int chunk = bc % NCHUNK, b = bc / NCHUNK;
    float A = -expf(A_log[d*D_STATE + n]);
    float Dv = Dp[d];
    float h = carry[t];
    int r0 = b*SEQ + chunk*CHUNK;
    for (int l = 0; l < CHUNK; l++){
        int r = r0 + l;
        float dtv = dt[(size_t)r*D_INNER + d];
        float xcv = xc[(size_t)r*D_INNER + d];
        float Bm  = dbc[(size_t)r*DBC_N + DT_RANK + n];
        float Cm  = dbc[(size_t)r*DBC_N + DT_RANK + D_STATE + n];
        float a = expf(dtv * A);
        h = a*h + dtv*xcv*Bm;
        float c = h * Cm;
        c += __shfl_xor(c, 1, 16);
        c += __shfl_xor(c, 2, 16);
        c += __shfl_xor(c, 4, 16);
        c += __shfl_xor(c, 8, 16);
        if (n == 0){
            float z = xz[(size_t)r*(2*D_INNER) + D_INNER + d];
            y[(size_t)r*D_INNER + d] = (c + Dv*xcv) * siluf(z);
        }
    }
}

extern "C" void kernel_launch(void* const* d_in, const int* in_sizes, int n_in,
                              void* d_out, int out_size, void* d_ws, size_t ws_size,
                              hipStream_t stream) {
    const float* x         = (const float*)d_in[0];
    const float* norm_w    = (const float*)d_in[1];
    const float* in_proj_w = (const float*)d_in[2];
    const float* conv_w    = (const float*)d_in[3];
    const float* conv_b    = (const float*)d_in[4];
    const float* x_proj_w  = (const float*)d_in[5];
    const float* dt_proj_w = (const float*)d_in[6];
    const float* dt_proj_b = (const float*)d_in[7];
    const float* A_log     = (const float*)d_in[8];
    const float* Dp        = (const float*)d_in[9];
    const float* out_proj_w= (const float*)d_in[10];
    float* out = (float*)d_out;

    float* ws  = (float*)d_ws;
    float* h   = ws;                               // 2048*768
    float* xz  = h   + (size_t)NROWS*D_MODEL;      // 2048*3072
    float* xc  = xz  + (size_t)NROWS*2*D_INNER;    // 2048*1536
    float* dbc = xc  + (size_t)NROWS*D_INNER;      // 2048*80
    float* dtb = dbc + (size_t)NROWS*DBC_N;        // 2048*1536
    float* y   = dtb + (size_t)NROWS*D_INNER;      // 2048*1536
    float* Ap  = y   + (size_t)NROWS*D_INNER;      // 786432
    float* Hl  = Ap  + (size_t)SCAN_T;             // 786432
    float* cr  = Hl  + (size_t)SCAN_T;             // 786432

    k_rmsnorm<<<NROWS, 256, 0, stream>>>(x, norm_w, h);

    dim3 g1(2*D_INNER/64, NROWS/64);   // (48, 32)
    k_gemm64<0><<<g1, 256, 0, stream>>>(h, in_proj_w, xz, nullptr,
                                        NROWS, 2*D_INNER, D_MODEL);

    k_conv<<<(NROWS*D_INNER)/256, 256, 0, stream>>>(xz, conv_w, conv_b, xc);

    k_xproj<<<NROWS, 128, 0, stream>>>(xc, x_proj_w, dbc);

    dim3 g2(D_INNER/256, NROWS);
    k_dtproj<<<g2, 256, 0, stream>>>(dbc, dt_proj_w, dt_proj_b, dtb);

    k_scanA<<<SCAN_T/256, 256, 0, stream>>>(dtb, xc, dbc, A_log, Ap, Hl);
    k_scanB<<<(BATCH*D_INNER*D_STATE)/256, 256, 0, stream>>>(Ap, Hl, cr);
    k_scanC<<<SCAN_T/256, 256, 0, stream>>>(dtb, xc, dbc, xz, A_log, Dp, cr, y);

    dim3 g3(D_MODEL/64, NROWS/64);     // (12, 32)
    k_gemm64<1><<<g3, 256, 0, stream>>>(y, out_proj_w, out, x,
                                        NROWS, D_MODEL, D_INNER);
}

// Round 4
// 344.514 us; speedup vs baseline: 3.5152x; 1.6156x over previous
//
#include <hip/hip_runtime.h>
#include <hip/hip_bf16.h>
#include <math.h>
#include <stdint.h>

#define D_MODEL 768
#define D_STATE 16
#define D_INNER 1536
#define DT_RANK 48
#define BATCH   2
#define SEQ     1024
#define NROWS   (BATCH*SEQ)      // 2048
#define DBC_N   80
#define DBC_NP  128              // padded N for xproj MFMA
#define NCHUNK  16
#define CHUNK   64
#define SCAN_T  (BATCH*NCHUNK*D_INNER*D_STATE)   // 786432

typedef short short8 __attribute__((ext_vector_type(8)));
typedef float floatx4 __attribute__((ext_vector_type(4)));

__device__ __forceinline__ float siluf(float x){ return x / (1.0f + expf(-x)); }
__device__ __forceinline__ short f2b(float f){
    union { __hip_bfloat16 h; short s; } u; u.h = __float2bfloat16(f); return u.s;
}
__device__ __forceinline__ float b2f(short s){
    union { short s; __hip_bfloat16 h; } u; u.s = s; return __bfloat162float(u.h);
}
__device__ __forceinline__ void gload_lds16(const void* g, void* l){
    auto gp = reinterpret_cast<const __attribute__((address_space(1))) uint32_t*>(
        reinterpret_cast<uintptr_t>(g));
    auto lp = reinterpret_cast<__attribute__((address_space(3))) uint32_t*>(
        reinterpret_cast<uintptr_t>(l));
    __builtin_amdgcn_global_load_lds(gp, lp, 16, 0, 0);
}

// ---------------- transpose + fp32->bf16 convert: in[R][C] -> out[Cout][R] ----
__global__ __launch_bounds__(256) void k_transpose(const float* __restrict__ in,
                                                   short* __restrict__ outT,
                                                   int R, int C, int Cout){
    __shared__ float tile[32][33];
    int c0 = blockIdx.x*32, r0 = blockIdx.y*32;
    int tx = threadIdx.x & 31, ty = threadIdx.x >> 5;   // ty 0..7
    #pragma unroll
    for (int p = 0; p < 4; p++){
        int r = r0 + ty + p*8, c = c0 + tx;
        tile[ty+p*8][tx] = (r < R && c < C) ? in[(size_t)r*C + c] : 0.f;
    }
    __syncthreads();
    #pragma unroll
    for (int p = 0; p < 4; p++){
        int c = c0 + ty + p*8;   // out row (= original col)
        int r = r0 + tx;         // out col (= original row)
        if (c < Cout && r < R)
            outT[(size_t)c*R + r] = f2b(tile[tx][ty+p*8]);
    }
}

// ---------------- RMSNorm -> bf16 ---------------------------------------------
__global__ __launch_bounds__(256) void k_rmsnorm(const float* __restrict__ x,
                                                 const float* __restrict__ w,
                                                 short* __restrict__ hb){
    int r = blockIdx.x;
    const float* xr = x + (size_t)r * D_MODEL;
    float v[3]; float ss = 0.f;
    #pragma unroll
    for (int i = 0; i < 3; i++){
        v[i] = xr[threadIdx.x + i*256];
        ss += v[i]*v[i];
    }
    #pragma unroll
    for (int o = 1; o < 64; o <<= 1) ss += __shfl_xor(ss, o, 64);
    __shared__ float red[4];
    int wave = threadIdx.x >> 6, lane = threadIdx.x & 63;
    if (lane == 0) red[wave] = ss;
    __syncthreads();
    float tot = red[0] + red[1] + red[2] + red[3];
    float scale = rsqrtf(tot * (1.0f/768.0f) + 1e-6f);
    #pragma unroll
    for (int i = 0; i < 3; i++){
        int idx = threadIdx.x + i*256;
        hb[(size_t)r*D_MODEL + idx] = f2b(v[i] * scale * w[idx]);
    }
}

// ---------------- MFMA bf16 GEMM, A[M][K] bf16, Bt[N][K] bf16, C fp32 ---------
// EPI=1: += residual. GUARD=1: store only n < Nld. ldc = Nld.
template<int BM, int BN, int EPI, int GUARD>
__global__ __launch_bounds__(256) void k_mfma_bt(const short* __restrict__ A,
                                                 const short* __restrict__ Bt,
                                                 float* __restrict__ C,
                                                 const float* __restrict__ res,
                                                 int M, int N, int K, int Nld){
    constexpr int WM = BM/2, WN = BN/2;
    constexpr int FM = WM/16, FN = WN/16;
    __shared__ short As[BM*32];
    __shared__ short Bs[BN*32];
    int t = threadIdx.x;
    int wave = t >> 6, lane = t & 63;
    int lm = lane & 15, lq = lane >> 4;
    int row0 = blockIdx.y * BM, col0 = blockIdx.x * BN;
    int wr = (wave >> 1) * WM, wc = (wave & 1) * WN;
    floatx4 acc[FM][FN];
    #pragma unroll
    for (int mi = 0; mi < FM; mi++)
        #pragma unroll
        for (int ni = 0; ni < FN; ni++)
            acc[mi][ni] = (floatx4){0.f,0.f,0.f,0.f};

    for (int k0 = 0; k0 < K; k0 += 32){
        #pragma unroll
        for (int r2 = 0; r2 < BM/64; r2++){
            int slot = r2*256 + t;
            int ar = slot >> 2, ak = (slot & 3)*8;
            gload_lds16(A + (size_t)(row0+ar)*K + k0 + ak, &As[slot*8]);
        }
        #pragma unroll
        for (int r2 = 0; r2 < BN/64; r2++){
            int slot = r2*256 + t;
            int br = slot >> 2, bk = (slot & 3)*8;
            gload_lds16(Bt + (size_t)(col0+br)*K + k0 + bk, &Bs[slot*8]);
        }
        __syncthreads();
        short8 af[FM], bfr[FN];
        #pragma unroll
        for (int mi = 0; mi < FM; mi++)
            af[mi] = *(const short8*)&As[(wr + mi*16 + lm)*32 + lq*8];
        #pragma unroll
        for (int ni = 0; ni < FN; ni++)
            bfr[ni] = *(const short8*)&Bs[(wc + ni*16 + lm)*32 + lq*8];
        #pragma unroll
        for (int mi = 0; mi < FM; mi++)
            #pragma unroll
            for (int ni = 0; ni < FN; ni++)
                acc[mi][ni] = __builtin_amdgcn_mfma_f32_16x16x32_bf16(
                                  af[mi], bfr[ni], acc[mi][ni], 0, 0, 0);
        __syncthreads();
    }
    // epilogue: C/D layout col=lane&15, row=lq*4+reg
    #pragma unroll
    for (int mi = 0; mi < FM; mi++)
        #pragma unroll
        for (int ni = 0; ni < FN; ni++)
            #pragma unroll
            for (int r = 0; r < 4; r++){
                int m = row0 + wr + mi*16 + lq*4 + r;
                int n = col0 + wc + ni*16 + lm;
                if (!GUARD || n < Nld){
                    float v = acc[mi][ni][r];
                    if (EPI == 1) v += res[(size_t)m*Nld + n];
                    C[(size_t)m*Nld + n] = v;
                }
            }
}

// ---------------- causal depthwise conv + bias + SiLU -> bf16 -----------------
__global__ __launch_bounds__(256) void k_conv(const float* __restrict__ xz,
                                              const float* __restrict__ cw,
                                              const float* __restrict__ cb,
                                              short* __restrict__ xcb){
    int idx = blockIdx.x * 256 + threadIdx.x;   // over NROWS*D_INNER
    int d = idx % D_INNER;
    int r = idx / D_INNER;
    int l = r % SEQ;
    float acc = cb[d];
    #pragma unroll
    for (int k = 0; k < 4; k++){
        int ls = l - 3 + k;
        if (ls >= 0)
            acc += xz[(size_t)(r - 3 + k)*3072 + d] * cw[d*4 + k];
    }
    xcb[idx] = f2b(siluf(acc));
}

// ---------------- dt-proj (K=48) + bias + softplus ----------------------------
__global__ __launch_bounds__(256) void k_dtproj(const float* __restrict__ dbc,
                                                const float* __restrict__ w,
                                                const float* __restrict__ bias,
                                                float* __restrict__ dt){
    int r = blockIdx.y;
    int j = blockIdx.x * 256 + threadIdx.x;   // 0..1535
    __shared__ float dl[DT_RANK];
    if (threadIdx.x < DT_RANK) dl[threadIdx.x] = dbc[(size_t)r*DBC_N + threadIdx.x];
    __syncthreads();
    float acc = bias[j];
    #pragma unroll
    for (int k = 0; k < DT_RANK; k++)
        acc += dl[k] * w[k*D_INNER + j];
    dt[(size_t)r*D_INNER + j] = (acc > 20.f) ? acc : log1pf(expf(acc));
}

// ================= chunked selective scan =====================================
__global__ __launch_bounds__(256) void k_scanA(const float* __restrict__ dt,
                                               const short* __restrict__ xcb,
                                               const float* __restrict__ dbc,
                                               const float* __restrict__ A_log,
                                               float* __restrict__ Aprod,
                                               float* __restrict__ Hloc){
    int t = blockIdx.x * 256 + threadIdx.x;
    int n = t & 15;
    int d = (t >> 4) % D_INNER;
    int bc = t / (16*D_INNER);
    int chunk = bc % NCHUNK, b = bc / NCHUNK;
    float A = -expf(A_log[d*D_STATE + n]);
    float aP = 1.f, h = 0.f;
    int r0 = b*SEQ + chunk*CHUNK;
    for (int l = 0; l < CHUNK; l++){
        int r = r0 + l;
        float dtv = dt[(size_t)r*D_INNER + d];
        float xcv = b2f(xcb[(size_t)r*D_INNER + d]);
        float Bm  = dbc[(size_t)r*DBC_N + DT_RANK + n];
        float a = expf(dtv * A);
        h = a*h + dtv*xcv*Bm;
        aP *= a;
    }
    Aprod[t] = aP;
    Hloc[t]  = h;
}

__global__ __launch_bounds__(256) void k_scanB(const float* __restrict__ Aprod,
                                               const float* __restrict__ Hloc,
                                               float* __restrict__ carry){
    int t = blockIdx.x * 256 + threadIdx.x;    // over [b][d][n] = 49152
    int dn = t % (D_INNER*16);
    int b  = t / (D_INNER*16);
    float c = 0.f;
    for (int ch = 0; ch < NCHUNK; ch++){
        size_t idx = ((size_t)(b*NCHUNK + ch))*(D_INNER*16) + dn;
        carry[idx] = c;
        c = Aprod[idx]*c + Hloc[idx];
    }
}

__global__ __launch_bounds__(256) void k_scanC(const float* __restrict__ dt,
                                               const short* __restrict__ xcb,
                                               const float* __restrict__ dbc,
                                               const float* __restrict__ xz,
                                               const float* __restrict__ A_log,
                                               const float* __restrict__ Dp,
                                               const float* __restrict__ carry,
                                               short* __restrict__ yb){
    int t = blockIdx.x * 256 + threadIdx.x;
    int n = t & 15;
    int d = (t >> 4) % D_INNER;
    int bc = t / (16*D_INNER);
    int chunk = bc % NCHUNK, b = bc / NCHUNK;
    float A = -expf(A_log[d*D_STATE + n]);
    float Dv = Dp[d];
    float h = carry[t];
    int r0 = b*SEQ + chunk*CHUNK;
    for (int l = 0; l < CHUNK; l++){
        int r = r0 + l;
        float dtv = dt[(size_t)r*D_INNER + d];
        float xcv = b2f(xcb[(size_t)r*D_INNER + d]);
        float Bm  = dbc[(size_t)r*DBC_N + DT_RANK + n];
        float Cm  = dbc[(size_t)r*DBC_N + DT_RANK + D_STATE + n];
        float a = expf(dtv * A);
        h = a*h + dtv*xcv*Bm;
        float c = h * Cm;
        c += __shfl_xor(c, 1, 16);
        c += __shfl_xor(c, 2, 16);
        c += __shfl_xor(c, 4, 16);
        c += __shfl_xor(c, 8, 16);
        if (n == 0){
            float z = xz[(size_t)r*(2*D_INNER) + D_INNER + d];
            yb[(size_t)r*D_INNER + d] = f2b((c + Dv*xcv) * siluf(z));
        }
    }
}

extern "C" void kernel_launch(void* const* d_in, const int* in_sizes, int n_in,
                              void* d_out, int out_size, void* d_ws, size_t ws_size,
                              hipStream_t stream) {
    const float* x         = (const float*)d_in[0];
    const float* norm_w    = (const float*)d_in[1];
    const float* in_proj_w = (const float*)d_in[2];
    const float* conv_w    = (const float*)d_in[3];
    const float* conv_b    = (const float*)d_in[4];
    const float* x_proj_w  = (const float*)d_in[5];
    const float* dt_proj_w = (const float*)d_in[6];
    const float* dt_proj_b = (const float*)d_in[7];
    const float* A_log     = (const float*)d_in[8];
    const float* Dp        = (const float*)d_in[9];
    const float* out_proj_w= (const float*)d_in[10];
    float* out = (float*)d_out;

    char* p = (char*)d_ws;
    short* hb  = (short*)p; p += (size_t)NROWS*D_MODEL*2;       // bf16 A for in-proj
    float* xz  = (float*)p; p += (size_t)NROWS*3072*4;          // in-proj out
    short* xcb = (short*)p; p += (size_t)NROWS*D_INNER*2;       // conv out bf16
    float* dbc = (float*)p; p += (size_t)NROWS*DBC_N*4;
    float* dtb = (float*)p; p += (size_t)NROWS*D_INNER*4;
    short* yb  = (short*)p; p += (size_t)NROWS*D_INNER*2;       // scan out bf16
    float* Ap  = (float*)p; p += (size_t)SCAN_T*4;
    float* Hl  = (float*)p; p += (size_t)SCAN_T*4;
    float* cr  = (float*)p; p += (size_t)SCAN_T*4;
    short* Wb1 = (short*)p; p += (size_t)3072*768*2;            // in_proj_w^T bf16
    short* Wb3 = (short*)p; p += (size_t)768*1536*2;            // out_proj_w^T bf16
    short* Wbx = (short*)p; p += (size_t)DBC_NP*1536*2;         // x_proj_w^T bf16 (zero-padded)

    // weight transposes (fp32 -> bf16, [K][N] -> [N][K])
    k_transpose<<<dim3(96, 24), 256, 0, stream>>>(in_proj_w,  Wb1, 768, 3072, 3072);
    k_transpose<<<dim3(24, 48), 256, 0, stream>>>(out_proj_w, Wb3, 1536, 768, 768);
    k_transpose<<<dim3(4, 48),  256, 0, stream>>>(x_proj_w,   Wbx, 1536, DBC_N, DBC_NP);

    k_rmsnorm<<<NROWS, 256, 0, stream>>>(x, norm_w, hb);

    // in-proj: M=2048, N=3072, K=768
    k_mfma_bt<128,128,0,0><<<dim3(3072/128, NROWS/128), 256, 0, stream>>>(
        hb, Wb1, xz, nullptr, NROWS, 3072, D_MODEL, 3072);

    k_conv<<<(NROWS*D_INNER)/256, 256, 0, stream>>>(xz, conv_w, conv_b, xcb);

    // x-proj: M=2048, N=128(pad of 80), K=1536
    k_mfma_bt<64,64,0,1><<<dim3(DBC_NP/64, NROWS/64), 256, 0, stream>>>(
        xcb, Wbx, dbc, nullptr, NROWS, DBC_NP, D_INNER, DBC_N);

    dim3 g2(D_INNER/256, NROWS);
    k_dtproj<<<g2, 256, 0, stream>>>(dbc, dt_proj_w, dt_proj_b, dtb);

    k_scanA<<<SCAN_T/256, 256, 0, stream>>>(dtb, xcb, dbc, A_log, Ap, Hl);
    k_scanB<<<(BATCH*D_INNER*D_STATE)/256, 256, 0, stream>>>(Ap, Hl, cr);
    k_scanC<<<SCAN_T/256, 256, 0, stream>>>(dtb, xcb, dbc, xz, A_log, Dp, cr, yb);

    // out-proj: M=2048, N=768, K=1536, residual add
    k_mfma_bt<64,64,1,0><<<dim3(768/64, NROWS/64), 256, 0, stream>>>(
        yb, Wb3, out, x, NROWS, 768, D_INNER, 768);
}

// Round 5
// 275.285 us; speedup vs baseline: 4.3991x; 1.2515x over previous
//
#include <hip/hip_runtime.h>
#include <hip/hip_bf16.h>
#include <math.h>
#include <stdint.h>

#define D_MODEL 768
#define D_STATE 16
#define D_INNER 1536
#define DT_RANK 48
#define BATCH   2
#define SEQ     1024
#define NROWS   (BATCH*SEQ)      // 2048
#define DBC_N   80
#define DBC_NP  128              // padded N for xproj MFMA
#define NCHUNK  64
#define CHUNK   16               // SEQ/NCHUNK
#define SCAN_G  (BATCH*NCHUNK*D_INNER)           // 196608 threads (A/C)
#define SCAN_T  ((size_t)SCAN_G*D_STATE)         // 3145728 elems (Aprod/Hloc)

typedef short short8 __attribute__((ext_vector_type(8)));
typedef float floatx4 __attribute__((ext_vector_type(4)));

__device__ __forceinline__ float siluf(float x){ return x / (1.0f + __expf(-x)); }
__device__ __forceinline__ short f2b(float f){
    union { __hip_bfloat16 h; short s; } u; u.h = __float2bfloat16(f); return u.s;
}
__device__ __forceinline__ float b2f(short s){
    union { short s; __hip_bfloat16 h; } u; u.s = s; return __bfloat162float(u.h);
}
__device__ __forceinline__ void gload_lds16(const void* g, void* l){
    auto gp = reinterpret_cast<const __attribute__((address_space(1))) uint32_t*>(
        reinterpret_cast<uintptr_t>(g));
    auto lp = reinterpret_cast<__attribute__((address_space(3))) uint32_t*>(
        reinterpret_cast<uintptr_t>(l));
    __builtin_amdgcn_global_load_lds(gp, lp, 16, 0, 0);
}

// ---------------- transpose + fp32->bf16 convert: in[R][C] -> out[Cout][R] ----
__global__ __launch_bounds__(256) void k_transpose(const float* __restrict__ in,
                                                   short* __restrict__ outT,
                                                   int R, int C, int Cout){
    __shared__ float tile[32][33];
    int c0 = blockIdx.x*32, r0 = blockIdx.y*32;
    int tx = threadIdx.x & 31, ty = threadIdx.x >> 5;   // ty 0..7
    #pragma unroll
    for (int p = 0; p < 4; p++){
        int r = r0 + ty + p*8, c = c0 + tx;
        tile[ty+p*8][tx] = (r < R && c < C) ? in[(size_t)r*C + c] : 0.f;
    }
    __syncthreads();
    #pragma unroll
    for (int p = 0; p < 4; p++){
        int c = c0 + ty + p*8;   // out row (= original col)
        int r = r0 + tx;         // out col (= original row)
        if (c < Cout && r < R)
            outT[(size_t)c*R + r] = f2b(tile[tx][ty+p*8]);
    }
}

// ---------------- RMSNorm -> bf16 ---------------------------------------------
__global__ __launch_bounds__(256) void k_rmsnorm(const float* __restrict__ x,
                                                 const float* __restrict__ w,
                                                 short* __restrict__ hb){
    int r = blockIdx.x;
    const float* xr = x + (size_t)r * D_MODEL;
    float v[3]; float ss = 0.f;
    #pragma unroll
    for (int i = 0; i < 3; i++){
        v[i] = xr[threadIdx.x + i*256];
        ss += v[i]*v[i];
    }
    #pragma unroll
    for (int o = 1; o < 64; o <<= 1) ss += __shfl_xor(ss, o, 64);
    __shared__ float red[4];
    int wave = threadIdx.x >> 6, lane = threadIdx.x & 63;
    if (lane == 0) red[wave] = ss;
    __syncthreads();
    float tot = red[0] + red[1] + red[2] + red[3];
    float scale = rsqrtf(tot * (1.0f/768.0f) + 1e-6f);
    #pragma unroll
    for (int i = 0; i < 3; i++){
        int idx = threadIdx.x + i*256;
        hb[(size_t)r*D_MODEL + idx] = f2b(v[i] * scale * w[idx]);
    }
}

// ---------------- MFMA bf16 GEMM, A[M][K] bf16, Bt[N][K] bf16, C fp32 ---------
template<int BM, int BN, int EPI, int GUARD>
__global__ __launch_bounds__(256) void k_mfma_bt(const short* __restrict__ A,
                                                 const short* __restrict__ Bt,
                                                 float* __restrict__ C,
                                                 const float* __restrict__ res,
                                                 int M, int N, int K, int Nld){
    constexpr int WM = BM/2, WN = BN/2;
    constexpr int FM = WM/16, FN = WN/16;
    __shared__ short As[BM*32];
    __shared__ short Bs[BN*32];
    int t = threadIdx.x;
    int wave = t >> 6, lane = t & 63;
    int lm = lane & 15, lq = lane >> 4;
    int row0 = blockIdx.y * BM, col0 = blockIdx.x * BN;
    int wr = (wave >> 1) * WM, wc = (wave & 1) * WN;
    floatx4 acc[FM][FN];
    #pragma unroll
    for (int mi = 0; mi < FM; mi++)
        #pragma unroll
        for (int ni = 0; ni < FN; ni++)
            acc[mi][ni] = (floatx4){0.f,0.f,0.f,0.f};

    for (int k0 = 0; k0 < K; k0 += 32){
        #pragma unroll
        for (int r2 = 0; r2 < BM/64; r2++){
            int slot = r2*256 + t;
            int ar = slot >> 2, ak = (slot & 3)*8;
            gload_lds16(A + (size_t)(row0+ar)*K + k0 + ak, &As[slot*8]);
        }
        #pragma unroll
        for (int r2 = 0; r2 < BN/64; r2++){
            int slot = r2*256 + t;
            int br = slot >> 2, bk = (slot & 3)*8;
            gload_lds16(Bt + (size_t)(col0+br)*K + k0 + bk, &Bs[slot*8]);
        }
        __syncthreads();
        short8 af[FM], bfr[FN];
        #pragma unroll
        for (int mi = 0; mi < FM; mi++)
            af[mi] = *(const short8*)&As[(wr + mi*16 + lm)*32 + lq*8];
        #pragma unroll
        for (int ni = 0; ni < FN; ni++)
            bfr[ni] = *(const short8*)&Bs[(wc + ni*16 + lm)*32 + lq*8];
        #pragma unroll
        for (int mi = 0; mi < FM; mi++)
            #pragma unroll
            for (int ni = 0; ni < FN; ni++)
                acc[mi][ni] = __builtin_amdgcn_mfma_f32_16x16x32_bf16(
                                  af[mi], bfr[ni], acc[mi][ni], 0, 0, 0);
        __syncthreads();
    }
    #pragma unroll
    for (int mi = 0; mi < FM; mi++)
        #pragma unroll
        for (int ni = 0; ni < FN; ni++)
            #pragma unroll
            for (int r = 0; r < 4; r++){
                int m = row0 + wr + mi*16 + lq*4 + r;
                int n = col0 + wc + ni*16 + lm;
                if (!GUARD || n < Nld){
                    float v = acc[mi][ni][r];
                    if (EPI == 1) v += res[(size_t)m*Nld + n];
                    C[(size_t)m*Nld + n] = v;
                }
            }
}

// ---------------- causal depthwise conv + bias + SiLU -> bf16 -----------------
__global__ __launch_bounds__(256) void k_conv(const float* __restrict__ xz,
                                              const float* __restrict__ cw,
                                              const float* __restrict__ cb,
                                              short* __restrict__ xcb){
    int idx = blockIdx.x * 256 + threadIdx.x;   // over NROWS*D_INNER
    int d = idx % D_INNER;
    int r = idx / D_INNER;
    int l = r % SEQ;
    float acc = cb[d];
    #pragma unroll
    for (int k = 0; k < 4; k++){
        int ls = l - 3 + k;
        if (ls >= 0)
            acc += xz[(size_t)(r - 3 + k)*3072 + d] * cw[d*4 + k];
    }
    xcb[idx] = f2b(siluf(acc));
}

// ---------------- dt-proj (K=48) + bias + softplus ----------------------------
__global__ __launch_bounds__(256) void k_dtproj(const float* __restrict__ dbc,
                                                const float* __restrict__ w,
                                                const float* __restrict__ bias,
                                                float* __restrict__ dt){
    int r = blockIdx.y;
    int j = blockIdx.x * 256 + threadIdx.x;   // 0..1535
    __shared__ float dl[DT_RANK];
    if (threadIdx.x < DT_RANK) dl[threadIdx.x] = dbc[(size_t)r*DBC_N + threadIdx.x];
    __syncthreads();
    float acc = bias[j];
    #pragma unroll
    for (int k = 0; k < DT_RANK; k++)
        acc += dl[k] * w[k*D_INNER + j];
    dt[(size_t)r*D_INNER + j] = (acc > 20.f) ? acc : log1pf(expf(acc));
}

// ================= chunked selective scan (16 states per thread) ==============
// thread t = (b*NCHUNK + chunk)*D_INNER + d   (d fastest -> coalesced dt/xc)
// Aprod/Hloc/carry layout: [t][n], contiguous 16 floats per thread.

__global__ __launch_bounds__(256) void k_scanA(const float* __restrict__ dt,
                                               const short* __restrict__ xcb,
                                               const float* __restrict__ dbc,
                                               const float* __restrict__ A_log,
                                               float* __restrict__ Aprod,
                                               float* __restrict__ Hloc){
    int t = blockIdx.x * 256 + threadIdx.x;
    int d = t % D_INNER;
    int bc = t / D_INNER;
    int chunk = bc % NCHUNK, b = bc / NCHUNK;
    float A[16], h[16], aP[16];
    const float4* al = (const float4*)&A_log[d*D_STATE];
    #pragma unroll
    for (int i = 0; i < 4; i++){
        float4 v = al[i];
        A[4*i+0] = -__expf(v.x); A[4*i+1] = -__expf(v.y);
        A[4*i+2] = -__expf(v.z); A[4*i+3] = -__expf(v.w);
    }
    #pragma unroll
    for (int n = 0; n < 16; n++){ h[n] = 0.f; aP[n] = 1.f; }
    int r0 = b*SEQ + chunk*CHUNK;
    for (int l = 0; l < CHUNK; l++){
        int r = r0 + l;
        float dtv = dt[(size_t)r*D_INNER + d];
        float xcv = b2f(xcb[(size_t)r*D_INNER + d]);
        const float4* bp = (const float4*)&dbc[(size_t)r*DBC_N + DT_RANK];
        float Bm[16];
        #pragma unroll
        for (int i = 0; i < 4; i++){
            float4 v = bp[i];
            Bm[4*i+0]=v.x; Bm[4*i+1]=v.y; Bm[4*i+2]=v.z; Bm[4*i+3]=v.w;
        }
        float comm = dtv * xcv;
        #pragma unroll
        for (int n = 0; n < 16; n++){
            float a = __expf(dtv * A[n]);
            h[n] = a*h[n] + comm*Bm[n];
            aP[n] *= a;
        }
    }
    float4* ap = (float4*)&Aprod[(size_t)t*16];
    float4* hp = (float4*)&Hloc[(size_t)t*16];
    #pragma unroll
    for (int i = 0; i < 4; i++){
        ap[i] = make_float4(aP[4*i], aP[4*i+1], aP[4*i+2], aP[4*i+3]);
        hp[i] = make_float4(h[4*i], h[4*i+1], h[4*i+2], h[4*i+3]);
    }
}

// carry may alias Aprod: reads happen before the write at each idx.
__global__ __launch_bounds__(256) void k_scanB(const float* Aprod,
                                               const float* Hloc,
                                               float* carry){
    int t = blockIdx.x * 256 + threadIdx.x;    // over [b][d][n] = 49152
    int dn = t % (D_INNER*16);
    int b  = t / (D_INNER*16);
    float c = 0.f;
    for (int ch = 0; ch < NCHUNK; ch++){
        size_t idx = ((size_t)((b*NCHUNK + ch)*D_INNER)*16) + dn;
        float a  = Aprod[idx];
        float hl = Hloc[idx];
        carry[idx] = c;
        c = a*c + hl;
    }
}

__global__ __launch_bounds__(256) void k_scanC(const float* __restrict__ dt,
                                               const short* __restrict__ xcb,
                                               const float* __restrict__ dbc,
                                               const float* __restrict__ xz,
                                               const float* __restrict__ A_log,
                                               const float* __restrict__ Dp,
                                               const float* __restrict__ carry,
                                               short* __restrict__ yb){
    int t = blockIdx.x * 256 + threadIdx.x;
    int d = t % D_INNER;
    int bc = t / D_INNER;
    int chunk = bc % NCHUNK, b = bc / NCHUNK;
    float A[16], h[16];
    const float4* al = (const float4*)&A_log[d*D_STATE];
    #pragma unroll
    for (int i = 0; i < 4; i++){
        float4 v = al[i];
        A[4*i+0] = -__expf(v.x); A[4*i+1] = -__expf(v.y);
        A[4*i+2] = -__expf(v.z); A[4*i+3] = -__expf(v.w);
    }
    const float4* cp = (const float4*)&carry[(size_t)t*16];
    #pragma unroll
    for (int i = 0; i < 4; i++){
        float4 v = cp[i];
        h[4*i+0]=v.x; h[4*i+1]=v.y; h[4*i+2]=v.z; h[4*i+3]=v.w;
    }
    float Dv = Dp[d];
    int r0 = b*SEQ + chunk*CHUNK;
    for (int l = 0; l < CHUNK; l++){
        int r = r0 + l;
        float dtv = dt[(size_t)r*D_INNER + d];
        float xcv = b2f(xcb[(size_t)r*D_INNER + d]);
        const float4* bp = (const float4*)&dbc[(size_t)r*DBC_N + DT_RANK];
        float Bm[16], Cm[16];
        #pragma unroll
        for (int i = 0; i < 4; i++){
            float4 v = bp[i];
            Bm[4*i+0]=v.x; Bm[4*i+1]=v.y; Bm[4*i+2]=v.z; Bm[4*i+3]=v.w;
            float4 w = bp[4+i];
            Cm[4*i+0]=w.x; Cm[4*i+1]=w.y; Cm[4*i+2]=w.z; Cm[4*i+3]=w.w;
        }
        float comm = dtv * xcv;
        float yv = 0.f;
        #pragma unroll
        for (int n = 0; n < 16; n++){
            float a = __expf(dtv * A[n]);
            h[n] = a*h[n] + comm*Bm[n];
            yv += h[n]*Cm[n];
        }
        float z = xz[(size_t)r*(2*D_INNER) + D_INNER + d];
        yb[(size_t)r*D_INNER + d] = f2b((yv + Dv*xcv) * siluf(z));
    }
}

extern "C" void kernel_launch(void* const* d_in, const int* in_sizes, int n_in,
                              void* d_out, int out_size, void* d_ws, size_t ws_size,
                              hipStream_t stream) {
    const float* x         = (const float*)d_in[0];
    const float* norm_w    = (const float*)d_in[1];
    const float* in_proj_w = (const float*)d_in[2];
    const float* conv_w    = (const float*)d_in[3];
    const float* conv_b    = (const float*)d_in[4];
    const float* x_proj_w  = (const float*)d_in[5];
    const float* dt_proj_w = (const float*)d_in[6];
    const float* dt_proj_b = (const float*)d_in[7];
    const float* A_log     = (const float*)d_in[8];
    const float* Dp        = (const float*)d_in[9];
    const float* out_proj_w= (const float*)d_in[10];
    float* out = (float*)d_out;

    char* p = (char*)d_ws;
    short* hb  = (short*)p; p += (size_t)NROWS*D_MODEL*2;
    float* xz  = (float*)p; p += (size_t)NROWS*3072*4;
    short* xcb = (short*)p; p += (size_t)NROWS*D_INNER*2;
    float* dbc = (float*)p; p += (size_t)NROWS*DBC_N*4;
    float* dtb = (float*)p; p += (size_t)NROWS*D_INNER*4;
    short* yb  = (short*)p; p += (size_t)NROWS*D_INNER*2;
    float* Ap  = (float*)p; p += SCAN_T*4;          // also reused as carry
    float* Hl  = (float*)p; p += SCAN_T*4;
    short* Wb1 = (short*)p; p += (size_t)3072*768*2;
    short* Wb3 = (short*)p; p += (size_t)768*1536*2;
    short* Wbx = (short*)p; p += (size_t)DBC_NP*1536*2;
    float* cr  = Ap;   // alias: k_scanB reads Aprod[idx] before writing carry[idx]

    k_transpose<<<dim3(96, 24), 256, 0, stream>>>(in_proj_w,  Wb1, 768, 3072, 3072);
    k_transpose<<<dim3(24, 48), 256, 0, stream>>>(out_proj_w, Wb3, 1536, 768, 768);
    k_transpose<<<dim3(4, 48),  256, 0, stream>>>(x_proj_w,   Wbx, 1536, DBC_N, DBC_NP);

    k_rmsnorm<<<NROWS, 256, 0, stream>>>(x, norm_w, hb);

    k_mfma_bt<128,128,0,0><<<dim3(3072/128, NROWS/128), 256, 0, stream>>>(
        hb, Wb1, xz, nullptr, NROWS, 3072, D_MODEL, 3072);

    k_conv<<<(NROWS*D_INNER)/256, 256, 0, stream>>>(xz, conv_w, conv_b, xcb);

    k_mfma_bt<64,64,0,1><<<dim3(DBC_NP/64, NROWS/64), 256, 0, stream>>>(
        xcb, Wbx, dbc, nullptr, NROWS, DBC_NP, D_INNER, DBC_N);

    dim3 g2(D_INNER/256, NROWS);
    k_dtproj<<<g2, 256, 0, stream>>>(dbc, dt_proj_w, dt_proj_b, dtb);

    k_scanA<<<SCAN_G/256, 256, 0, stream>>>(dtb, xcb, dbc, A_log, Ap, Hl);
    k_scanB<<<(BATCH*D_INNER*D_STATE)/256, 256, 0, stream>>>(Ap, Hl, cr);
    k_scanC<<<SCAN_G/256, 256, 0, stream>>>(dtb, xcb, dbc, xz, A_log, Dp, cr, yb);

    k_mfma_bt<64,64,1,0><<<dim3(768/64, NROWS/64), 256, 0, stream>>>(
        yb, Wb3, out, x, NROWS, 768, D_INNER, 768);
}

// Round 6
// 254.451 us; speedup vs baseline: 4.7594x; 1.0819x over previous
//
#include <hip/hip_runtime.h>
#include <hip/hip_bf16.h>
#include <math.h>
#include <stdint.h>

#define D_MODEL 768
#define D_STATE 16
#define D_INNER 1536
#define DT_RANK 48
#define BATCH   2
#define SEQ     1024
#define NROWS   (BATCH*SEQ)      // 2048
#define DBC_N   80
#define DBC_NP  128              // padded N for xproj MFMA
#define NCHUNK  64
#define CHUNK   16               // SEQ/NCHUNK
#define SCAN_G  (BATCH*NCHUNK*D_INNER)           // 196608 threads (A/C)
#define SCAN_T  ((size_t)SCAN_G*D_STATE)         // 3145728 elems (Aprod/Hloc)

typedef short short8 __attribute__((ext_vector_type(8)));
typedef float floatx4 __attribute__((ext_vector_type(4)));

__device__ __forceinline__ float siluf(float x){ return x / (1.0f + __expf(-x)); }
__device__ __forceinline__ short f2b(float f){
    union { __hip_bfloat16 h; short s; } u; u.h = __float2bfloat16(f); return u.s;
}
__device__ __forceinline__ float b2f(short s){
    union { short s; __hip_bfloat16 h; } u; u.s = s; return __bfloat162float(u.h);
}
__device__ __forceinline__ void gload_lds16(const void* g, void* l){
    auto gp = reinterpret_cast<const __attribute__((address_space(1))) uint32_t*>(
        reinterpret_cast<uintptr_t>(g));
    auto lp = reinterpret_cast<__attribute__((address_space(3))) uint32_t*>(
        reinterpret_cast<uintptr_t>(l));
    __builtin_amdgcn_global_load_lds(gp, lp, 16, 0, 0);
}

// ---------------- prep: 3 weight transposes (fp32->bf16) + dbc zeroing -------
// transpose: in[R][C] -> outT[Cout][R] (zero-pad C..Cout)
__device__ __forceinline__ void transp32(const float* in, short* outT,
                                         int R, int C, int Cout,
                                         int bx, int by, int t,
                                         float (*tile)[33]){
    int c0 = bx*32, r0 = by*32;
    int tx = t & 31, ty = t >> 5;
    #pragma unroll
    for (int p = 0; p < 4; p++){
        int r = r0 + ty + p*8, c = c0 + tx;
        tile[ty+p*8][tx] = (r < R && c < C) ? in[(size_t)r*C + c] : 0.f;
    }
    __syncthreads();
    #pragma unroll
    for (int p = 0; p < 4; p++){
        int c = c0 + ty + p*8;
        int r = r0 + tx;
        if (c < Cout && r < R)
            outT[(size_t)c*R + r] = f2b(tile[tx][ty+p*8]);
    }
}

// grid.x = 2304 + 1152 + 192 + 160 = 3808
__global__ __launch_bounds__(256) void k_prep(const float* __restrict__ w1, short* __restrict__ Wb1,
                                              const float* __restrict__ w3, short* __restrict__ Wb3,
                                              const float* __restrict__ wx, short* __restrict__ Wbx,
                                              float* __restrict__ dbc){
    __shared__ float tile[32][33];
    int bid = blockIdx.x, t = threadIdx.x;
    if (bid < 2304){
        transp32(w1, Wb1, 768, 3072, 3072, bid % 96, bid / 96, t, tile);
    } else if (bid < 3456){
        int id = bid - 2304;
        transp32(w3, Wb3, 1536, 768, 768, id % 24, id / 24, t, tile);
    } else if (bid < 3648){
        int id = bid - 3456;
        transp32(wx, Wbx, 1536, DBC_N, DBC_NP, id % 4, id / 4, t, tile);
    } else {
        int id = bid - 3648;                      // 160 blocks zero 2048*80 floats
        size_t base = (size_t)id*1024 + t*4;
        float4* p = (float4*)&dbc[base];
        *p = make_float4(0.f,0.f,0.f,0.f);
    }
}

// ---------------- RMSNorm -> bf16 ---------------------------------------------
__global__ __launch_bounds__(256) void k_rmsnorm(const float* __restrict__ x,
                                                 const float* __restrict__ w,
                                                 short* __restrict__ hb){
    int r = blockIdx.x;
    const float* xr = x + (size_t)r * D_MODEL;
    float v[3]; float ss = 0.f;
    #pragma unroll
    for (int i = 0; i < 3; i++){
        v[i] = xr[threadIdx.x + i*256];
        ss += v[i]*v[i];
    }
    #pragma unroll
    for (int o = 1; o < 64; o <<= 1) ss += __shfl_xor(ss, o, 64);
    __shared__ float red[4];
    int wave = threadIdx.x >> 6, lane = threadIdx.x & 63;
    if (lane == 0) red[wave] = ss;
    __syncthreads();
    float tot = red[0] + red[1] + red[2] + red[3];
    float scale = rsqrtf(tot * (1.0f/768.0f) + 1e-6f);
    #pragma unroll
    for (int i = 0; i < 3; i++){
        int idx = threadIdx.x + i*256;
        hb[(size_t)r*D_MODEL + idx] = f2b(v[i] * scale * w[idx]);
    }
}

// ---------------- MFMA bf16 GEMM, A[M][K] bf16, Bt[N][K] bf16 -----------------
// MODE 0: fp32 store. 1: fp32 store + residual. 2: bf16 store.
// MODE 3: fp32 atomicAdd, only n < Nld (split-K; C must be pre-zeroed).
template<int BM, int BN, int MODE, int KSPLIT>
__global__ __launch_bounds__(256) void k_mfma_bt(const short* __restrict__ A,
                                                 const short* __restrict__ Bt,
                                                 void* __restrict__ Cv,
                                                 const float* __restrict__ res,
                                                 int M, int N, int K, int Nld){
    constexpr int WM = BM/2, WN = BN/2;
    constexpr int FM = WM/16, FN = WN/16;
    constexpr int AU = BM*4;   // 16B staging units
    constexpr int BU = BN*4;
    __shared__ short As[BM*32];
    __shared__ short Bs[BN*32];
    int t = threadIdx.x;
    int wave = t >> 6, lane = t & 63;
    int lm = lane & 15, lq = lane >> 4;
    int row0 = blockIdx.y * BM, col0 = blockIdx.x * BN;
    int wr = (wave >> 1) * WM, wc = (wave & 1) * WN;
    int kper = K / KSPLIT;
    int kbeg = blockIdx.z * kper;
    floatx4 acc[FM][FN];
    #pragma unroll
    for (int mi = 0; mi < FM; mi++)
        #pragma unroll
        for (int ni = 0; ni < FN; ni++)
            acc[mi][ni] = (floatx4){0.f,0.f,0.f,0.f};

    for (int k0 = kbeg; k0 < kbeg + kper; k0 += 32){
        if constexpr (AU >= 256){
            #pragma unroll
            for (int r2 = 0; r2 < AU/256; r2++){
                int slot = r2*256 + t;
                int ar = slot >> 2, ak = (slot & 3)*8;
                gload_lds16(A + (size_t)(row0+ar)*K + k0 + ak, &As[slot*8]);
            }
        } else {
            if (t < AU){
                int ar = t >> 2, ak = (t & 3)*8;
                gload_lds16(A + (size_t)(row0+ar)*K + k0 + ak, &As[t*8]);
            }
        }
        if constexpr (BU >= 256){
            #pragma unroll
            for (int r2 = 0; r2 < BU/256; r2++){
                int slot = r2*256 + t;
                int br = slot >> 2, bk = (slot & 3)*8;
                gload_lds16(Bt + (size_t)(col0+br)*K + k0 + bk, &Bs[slot*8]);
            }
        } else {
            if (t < BU){
                int br = t >> 2, bk = (t & 3)*8;
                gload_lds16(Bt + (size_t)(col0+br)*K + k0 + bk, &Bs[t*8]);
            }
        }
        __syncthreads();
        short8 af[FM], bfr[FN];
        #pragma unroll
        for (int mi = 0; mi < FM; mi++)
            af[mi] = *(const short8*)&As[(wr + mi*16 + lm)*32 + lq*8];
        #pragma unroll
        for (int ni = 0; ni < FN; ni++)
            bfr[ni] = *(const short8*)&Bs[(wc + ni*16 + lm)*32 + lq*8];
        #pragma unroll
        for (int mi = 0; mi < FM; mi++)
            #pragma unroll
            for (int ni = 0; ni < FN; ni++)
                acc[mi][ni] = __builtin_amdgcn_mfma_f32_16x16x32_bf16(
                                  af[mi], bfr[ni], acc[mi][ni], 0, 0, 0);
        __syncthreads();
    }
    float* Cf = (float*)Cv;
    short* Cs = (short*)Cv;
    #pragma unroll
    for (int mi = 0; mi < FM; mi++)
        #pragma unroll
        for (int ni = 0; ni < FN; ni++)
            #pragma unroll
            for (int r = 0; r < 4; r++){
                int m = row0 + wr + mi*16 + lq*4 + r;
                int n = col0 + wc + ni*16 + lm;
                float v = acc[mi][ni][r];
                if constexpr (MODE == 0){
                    Cf[(size_t)m*Nld + n] = v;
                } else if constexpr (MODE == 1){
                    Cf[(size_t)m*Nld + n] = v + res[(size_t)m*Nld + n];
                } else if constexpr (MODE == 2){
                    Cs[(size_t)m*Nld + n] = f2b(v);
                } else {
                    if (n < Nld) atomicAdd(&Cf[(size_t)m*Nld + n], v);
                }
            }
}

// ---------------- causal depthwise conv + bias + SiLU -> bf16 -----------------
__global__ __launch_bounds__(256) void k_conv(const short* __restrict__ xzb,
                                              const float* __restrict__ cw,
                                              const float* __restrict__ cb,
                                              short* __restrict__ xcb){
    int idx = blockIdx.x * 256 + threadIdx.x;   // over NROWS*D_INNER
    int d = idx % D_INNER;
    int r = idx / D_INNER;
    int l = r % SEQ;
    float acc = cb[d];
    #pragma unroll
    for (int k = 0; k < 4; k++){
        int ls = l - 3 + k;
        if (ls >= 0)
            acc += b2f(xzb[(size_t)(r - 3 + k)*3072 + d]) * cw[d*4 + k];
    }
    xcb[idx] = f2b(siluf(acc));
}

// ---------------- dt-proj (K=48) + bias + softplus ----------------------------
__global__ __launch_bounds__(256) void k_dtproj(const float* __restrict__ dbc,
                                                const float* __restrict__ w,
                                                const float* __restrict__ bias,
                                                float* __restrict__ dt){
    int r = blockIdx.y;
    int j = blockIdx.x * 256 + threadIdx.x;   // 0..1535
    __shared__ float dl[DT_RANK];
    if (threadIdx.x < DT_RANK) dl[threadIdx.x] = dbc[(size_t)r*DBC_N + threadIdx.x];
    __syncthreads();
    float acc = bias[j];
    #pragma unroll
    for (int k = 0; k < DT_RANK; k++)
        acc += dl[k] * w[k*D_INNER + j];
    dt[(size_t)r*D_INNER + j] = (acc > 20.f) ? acc : log1pf(expf(acc));
}

// ================= chunked selective scan (16 states per thread) ==============
// thread t = (b*NCHUNK + chunk)*D_INNER + d   (d fastest -> coalesced dt/xc)
// Aprod/Hloc/carry layout: [t][n], contiguous 16 floats per thread.

__global__ __launch_bounds__(256) void k_scanA(const float* __restrict__ dt,
                                               const short* __restrict__ xcb,
                                               const float* __restrict__ dbc,
                                               const float* __restrict__ A_log,
                                               float* __restrict__ Aprod,
                                               float* __restrict__ Hloc){
    int t = blockIdx.x * 256 + threadIdx.x;
    int d = t % D_INNER;
    int bc = t / D_INNER;
    int chunk = bc % NCHUNK, b = bc / NCHUNK;
    float A[16], h[16], aP[16];
    const float4* al = (const float4*)&A_log[d*D_STATE];
    #pragma unroll
    for (int i = 0; i < 4; i++){
        float4 v = al[i];
        A[4*i+0] = -__expf(v.x); A[4*i+1] = -__expf(v.y);
        A[4*i+2] = -__expf(v.z); A[4*i+3] = -__expf(v.w);
    }
    #pragma unroll
    for (int n = 0; n < 16; n++){ h[n] = 0.f; aP[n] = 1.f; }
    int r0 = b*SEQ + chunk*CHUNK;
    for (int l = 0; l < CHUNK; l++){
        int r = r0 + l;
        float dtv = dt[(size_t)r*D_INNER + d];
        float xcv = b2f(xcb[(size_t)r*D_INNER + d]);
        const float4* bp = (const float4*)&dbc[(size_t)r*DBC_N + DT_RANK];
        float Bm[16];
        #pragma unroll
        for (int i = 0; i < 4; i++){
            float4 v = bp[i];
            Bm[4*i+0]=v.x; Bm[4*i+1]=v.y; Bm[4*i+2]=v.z; Bm[4*i+3]=v.w;
        }
        float comm = dtv * xcv;
        #pragma unroll
        for (int n = 0; n < 16; n++){
            float a = __expf(dtv * A[n]);
            h[n] = a*h[n] + comm*Bm[n];
            aP[n] *= a;
        }
    }
    float4* ap = (float4*)&Aprod[(size_t)t*16];
    float4* hp = (float4*)&Hloc[(size_t)t*16];
    #pragma unroll
    for (int i = 0; i < 4; i++){
        ap[i] = make_float4(aP[4*i], aP[4*i+1], aP[4*i+2], aP[4*i+3]);
        hp[i] = make_float4(h[4*i], h[4*i+1], h[4*i+2], h[4*i+3]);
    }
}

// carry aliases Aprod: reads happen before the write at each idx.
__global__ __launch_bounds__(256) void k_scanB(const float* Aprod,
                                               const float* Hloc,
                                               float* carry){
    int t = blockIdx.x * 256 + threadIdx.x;    // over [b][d][n] = 49152
    int dn = t % (D_INNER*16);
    int b  = t / (D_INNER*16);
    float c = 0.f;
    for (int ch = 0; ch < NCHUNK; ch++){
        size_t idx = ((size_t)((b*NCHUNK + ch)*D_INNER)*16) + dn;
        float a  = Aprod[idx];
        float hl = Hloc[idx];
        carry[idx] = c;
        c = a*c + hl;
    }
}

__global__ __launch_bounds__(256) void k_scanC(const float* __restrict__ dt,
                                               const short* __restrict__ xcb,
                                               const float* __restrict__ dbc,
                                               const short* __restrict__ xzb,
                                               const float* __restrict__ A_log,
                                               const float* __restrict__ Dp,
                                               const float* __restrict__ carry,
                                               short* __restrict__ yb){
    int t = blockIdx.x * 256 + threadIdx.x;
    int d = t % D_INNER;
    int bc = t / D_INNER;
    int chunk = bc % NCHUNK, b = bc / NCHUNK;
    float A[16], h[16];
    const float4* al = (const float4*)&A_log[d*D_STATE];
    #pragma unroll
    for (int i = 0; i < 4; i++){
        float4 v = al[i];
        A[4*i+0] = -__expf(v.x); A[4*i+1] = -__expf(v.y);
        A[4*i+2] = -__expf(v.z); A[4*i+3] = -__expf(v.w);
    }
    const float4* cp = (const float4*)&carry[(size_t)t*16];
    #pragma unroll
    for (int i = 0; i < 4; i++){
        float4 v = cp[i];
        h[4*i+0]=v.x; h[4*i+1]=v.y; h[4*i+2]=v.z; h[4*i+3]=v.w;
    }
    float Dv = Dp[d];
    int r0 = b*SEQ + chunk*CHUNK;
    for (int l = 0; l < CHUNK; l++){
        int r = r0 + l;
        float dtv = dt[(size_t)r*D_INNER + d];
        float xcv = b2f(xcb[(size_t)r*D_INNER + d]);
        const float4* bp = (const float4*)&dbc[(size_t)r*DBC_N + DT_RANK];
        float Bm[16], Cm[16];
        #pragma unroll
        for (int i = 0; i < 4; i++){
            float4 v = bp[i];
            Bm[4*i+0]=v.x; Bm[4*i+1]=v.y; Bm[4*i+2]=v.z; Bm[4*i+3]=v.w;
            float4 w = bp[4+i];
            Cm[4*i+0]=w.x; Cm[4*i+1]=w.y; Cm[4*i+2]=w.z; Cm[4*i+3]=w.w;
        }
        float comm = dtv * xcv;
        float yv = 0.f;
        #pragma unroll
        for (int n = 0; n < 16; n++){
            float a = __expf(dtv * A[n]);
            h[n] = a*h[n] + comm*Bm[n];
            yv += h[n]*Cm[n];
        }
        float z = b2f(xzb[(size_t)r*(2*D_INNER) + D_INNER + d]);
        yb[(size_t)r*D_INNER + d] = f2b((yv + Dv*xcv) * siluf(z));
    }
}

extern "C" void kernel_launch(void* const* d_in, const int* in_sizes, int n_in,
                              void* d_out, int out_size, void* d_ws, size_t ws_size,
                              hipStream_t stream) {
    const float* x         = (const float*)d_in[0];
    const float* norm_w    = (const float*)d_in[1];
    const float* in_proj_w = (const float*)d_in[2];
    const float* conv_w    = (const float*)d_in[3];
    const float* conv_b    = (const float*)d_in[4];
    const float* x_proj_w  = (const float*)d_in[5];
    const float* dt_proj_w = (const float*)d_in[6];
    const float* dt_proj_b = (const float*)d_in[7];
    const float* A_log     = (const float*)d_in[8];
    const float* Dp        = (const float*)d_in[9];
    const float* out_proj_w= (const float*)d_in[10];
    float* out = (float*)d_out;

    char* p = (char*)d_ws;
    short* hb  = (short*)p; p += (size_t)NROWS*D_MODEL*2;
    short* xzb = (short*)p; p += (size_t)NROWS*3072*2;         // in-proj out (bf16)
    short* xcb = (short*)p; p += (size_t)NROWS*D_INNER*2;
    float* dbc = (float*)p; p += (size_t)NROWS*DBC_N*4;
    float* dtb = (float*)p; p += (size_t)NROWS*D_INNER*4;
    short* yb  = (short*)p; p += (size_t)NROWS*D_INNER*2;
    float* Ap  = (float*)p; p += SCAN_T*4;          // reused as carry
    float* Hl  = (float*)p; p += SCAN_T*4;
    short* Wb1 = (short*)p; p += (size_t)3072*768*2;
    short* Wb3 = (short*)p; p += (size_t)768*1536*2;
    short* Wbx = (short*)p; p += (size_t)DBC_NP*1536*2;
    float* cr  = Ap;   // alias: k_scanB reads before writing at each idx

    // transposes + dbc zero (dbc must be zero before split-K atomics)
    k_prep<<<3808, 256, 0, stream>>>(in_proj_w, Wb1, out_proj_w, Wb3,
                                     x_proj_w, Wbx, dbc);

    k_rmsnorm<<<NROWS, 256, 0, stream>>>(x, norm_w, hb);

    // in-proj: M=2048, N=3072, K=768, 128x64 tiles -> 768 blocks, bf16 out
    k_mfma_bt<128,64,2,1><<<dim3(3072/64, NROWS/128), 256, 0, stream>>>(
        hb, Wb1, xzb, nullptr, NROWS, 3072, D_MODEL, 3072);

    k_conv<<<(NROWS*D_INNER)/256, 256, 0, stream>>>(xzb, conv_w, conv_b, xcb);

    // x-proj: M=2048, N=128(pad of 80), K=1536, split-K=8 -> 512 blocks
    k_mfma_bt<64,64,3,8><<<dim3(DBC_NP/64, NROWS/64, 8), 256, 0, stream>>>(
        xcb, Wbx, dbc, nullptr, NROWS, DBC_NP, D_INNER, DBC_N);

    dim3 g2(D_INNER/256, NROWS);
    k_dtproj<<<g2, 256, 0, stream>>>(dbc, dt_proj_w, dt_proj_b, dtb);

    k_scanA<<<SCAN_G/256, 256, 0, stream>>>(dtb, xcb, dbc, A_log, Ap, Hl);
    k_scanB<<<(BATCH*D_INNER*D_STATE)/256, 256, 0, stream>>>(Ap, Hl, cr);
    k_scanC<<<SCAN_G/256, 256, 0, stream>>>(dtb, xcb, dbc, xzb, A_log, Dp, cr, yb);

    // out-proj: M=2048, N=768, K=1536, 32x64 tiles -> 768 blocks, +residual
    k_mfma_bt<32,64,1,1><<<dim3(768/64, NROWS/32), 256, 0, stream>>>(
        yb, Wb3, out, x, NROWS, 768, D_INNER, 768);
}